// Round 19
// baseline (122.933 us; speedup 1.0000x reference)
//
#include <hip/hip_runtime.h>
#include <stdint.h>
#include <stddef.h>

typedef __bf16 bf16;
typedef __bf16 bf16x2 __attribute__((ext_vector_type(2)));
typedef __bf16 bf16x4 __attribute__((ext_vector_type(4)));
typedef __bf16 bf16x8 __attribute__((ext_vector_type(8)));
typedef float f32x2 __attribute__((ext_vector_type(2)));
typedef float f32x4 __attribute__((ext_vector_type(4)));
typedef float f32x16 __attribute__((ext_vector_type(16)));

constexpr int Bb = 2, Nn = 2048, HID = 1024, Hh = 16, DH = 64;
constexpr int MTOK = Bb * Nn;   // 4096
constexpr int E3 = 3 * Hh * DH; // 3072

// ---------------- merged cast f32 -> bf16 (x, Wqkv, Wout in one launch) ----------------
__global__ void cast3_kernel(const float* __restrict__ x, const float* __restrict__ wqkv,
                             const float* __restrict__ wout,
                             bf16* __restrict__ xb, bf16* __restrict__ wqkvb,
                             bf16* __restrict__ woutb) {
  constexpr int N1 = MTOK * HID / 4;        // x float4s
  constexpr int N2 = N1 + E3 * HID / 4;     // + Wqkv
  int i = blockIdx.x * 256 + threadIdx.x;   // 0 .. 2097151
  const float* src;
  bf16* dst;
  int off;
  if (i < N1)      { src = x;    dst = xb;    off = i; }
  else if (i < N2) { src = wqkv; dst = wqkvb; off = i - N1; }
  else             { src = wout; dst = woutb; off = i - N2; }
  f32x4 v = reinterpret_cast<const f32x4*>(src)[off];
  bf16x4 o;
#pragma unroll
  for (int j = 0; j < 4; ++j) o[j] = (bf16)v[j];
  reinterpret_cast<bf16x4*>(dst)[off] = o;
}

// ---------------- BT GEMM: C[M,N] = A[M,K] * Bt[N,K]^T ----------------
// BK=64 via two 32-col halves per K-step (R15-proven); 32 MFMA per barrier pair.
template <bool OUT_BF16>
__global__ __launch_bounds__(256) void gemm_bt(const bf16* __restrict__ A,
                                               const bf16* __restrict__ Bt,
                                               void* __restrict__ Cp,
                                               int M, int N, int K) {
  __shared__ __align__(16) bf16 As[2][128 * 32];
  __shared__ __align__(16) bf16 Bs[2][128 * 32];
  const int tid = threadIdx.x;
  const int lane = tid & 63;
  const int wave = tid >> 6;
  const int wr = wave >> 1, wc = wave & 1;
  const int bm = blockIdx.x, bn = blockIdx.y;
  const int frow = lane & 15;
  const int fk = (lane >> 4) * 8;
  const int c0 = wave * 128 + lane;

  f32x4 acc[4][4] = {};

  for (int k0 = 0; k0 < K; k0 += 64) {
#pragma unroll
    for (int hk = 0; hk < 2; ++hk)
#pragma unroll
      for (int i = 0; i < 2; ++i) {
        int c = c0 + i * 64;             // chunk 0..511 within the half, 16B each
        int row = c >> 2;
        int col = (c & 3) * 8;
        const bf16* ga = A + (size_t)(bm * 128 + row) * K + k0 + hk * 32 + col;
        const bf16* gb = Bt + (size_t)(bn * 128 + row) * K + k0 + hk * 32 + col;
        __builtin_amdgcn_global_load_lds((const __attribute__((address_space(1))) void*)ga,
                                         (__attribute__((address_space(3))) void*)(As[hk] + c * 8),
                                         16, 0, 0);
        __builtin_amdgcn_global_load_lds((const __attribute__((address_space(1))) void*)gb,
                                         (__attribute__((address_space(3))) void*)(Bs[hk] + c * 8),
                                         16, 0, 0);
      }
    __syncthreads();
#pragma unroll
    for (int hk = 0; hk < 2; ++hk) {
      bf16x8 af[4], bfr[4];
#pragma unroll
      for (int m = 0; m < 4; ++m)
        af[m] = *reinterpret_cast<const bf16x8*>(As[hk] + (wr * 64 + m * 16 + frow) * 32 + fk);
#pragma unroll
      for (int n = 0; n < 4; ++n)
        bfr[n] = *reinterpret_cast<const bf16x8*>(Bs[hk] + (wc * 64 + n * 16 + frow) * 32 + fk);
#pragma unroll
      for (int m = 0; m < 4; ++m)
#pragma unroll
        for (int n = 0; n < 4; ++n)
          acc[m][n] = __builtin_amdgcn_mfma_f32_16x16x32_bf16(af[m], bfr[n], acc[m][n], 0, 0, 0);
    }
    __syncthreads();
  }

  const int r0 = bm * 128 + wr * 64;
  const int cc0 = bn * 128 + wc * 64;
#pragma unroll
  for (int m = 0; m < 4; ++m)
#pragma unroll
    for (int n = 0; n < 4; ++n)
#pragma unroll
      for (int r = 0; r < 4; ++r) {
        int row = r0 + m * 16 + (lane >> 4) * 4 + r;
        int col = cc0 + n * 16 + frow;
        if (OUT_BF16)
          ((bf16*)Cp)[(size_t)row * N + col] = (bf16)acc[m][n][r];
        else
          ((float*)Cp)[(size_t)row * N + col] = acc[m][n][r];
      }
}

// K-row permutation: slot a holds key kappa(a); makes the S^T accumulator land
// directly in the PV B-fragment layout (no cross-lane exchange needed).
__device__ __forceinline__ int kappa(int a) {
  return (((a >> 2) ^ (a >> 3)) & 1) ? (a ^ 12) : a;
}

// ---------------- RoPE + fragment-pack ----------------
// Emits Q,K,V in MFMA-fragment-packed order so attention loads are base+lane*16B (coalesced).
// K rows kappa-permuted within each 32-row block. Q pre-scaled by dh^-0.5*log2(e).
__global__ __launch_bounds__(256) void rope_pack(const bf16* __restrict__ qkvb,
                                                 const float* __restrict__ rope,
                                                 bf16* __restrict__ qpk,
                                                 bf16* __restrict__ kpk,
                                                 bf16* __restrict__ vpk) {
  __shared__ bf16 qs[128][66];
  __shared__ bf16 ks[128][66];
  __shared__ bf16 vs[128][66];
  const int bh = blockIdx.y;
  const int b = bh >> 4;
  const int h = bh & 15;
  const int n0 = blockIdx.x * 128;
  const int t = threadIdx.x;

  constexpr float QS = 0.125f * 1.44269504088896340736f;  // folded into Q

  // phase A: rope + stage to LDS
  for (int it = 0; it < 16; ++it) {
    int p = it * 256 + t;   // (row 0..127) x (pair 0..31)
    int nl = p >> 5, i = p & 31;
    int n = n0 + nl;
    size_t rowbase = (size_t)(b * Nn + n);
    const bf16* src = qkvb + rowbase * E3 + h * DH + 2 * i;
    f32x2 cs = *reinterpret_cast<const f32x2*>(rope + rowbase * DH + 2 * i);
    float c = cs[0], sn = cs[1];
    bf16x2 qv = *reinterpret_cast<const bf16x2*>(src);
    bf16x2 kv = *reinterpret_cast<const bf16x2*>(src + HID);
    bf16x2 vv = *reinterpret_cast<const bf16x2*>(src + 2 * HID);
    float q0 = (float)qv[0], q1 = (float)qv[1];
    float k0 = (float)kv[0], k1 = (float)kv[1];
    qs[nl][2 * i]     = (bf16)((q0 * c - q1 * sn) * QS);
    qs[nl][2 * i + 1] = (bf16)((q1 * c + q0 * sn) * QS);
    ks[nl][2 * i]     = (bf16)(k0 * c - k1 * sn);
    ks[nl][2 * i + 1] = (bf16)(k1 * c + k0 * sn);
    vs[nl][2 * i]     = vv[0];
    vs[nl][2 * i + 1] = vv[1];
  }
  __syncthreads();

  // phase B1: q/k fragment-pack (coalesced 16B stores); K rows kappa-permuted
  const int lane2 = t & 63;
  const int dd = t >> 6;              // 0..3
  const int lo2 = lane2 & 31, hi2 = lane2 >> 5;
  const int lok = kappa(lo2);
#pragma unroll
  for (int kbq = 0; kbq < 4; ++kbq) {
    int col = dd * 16 + hi2 * 8;
    bf16x8 q8 = *reinterpret_cast<const bf16x8*>(&qs[kbq * 32 + lo2][col]);
    bf16x8 k8 = *reinterpret_cast<const bf16x8*>(&ks[kbq * 32 + lok][col]);
    size_t base = ((((size_t)bh * 64 + (n0 >> 5) + kbq) * 4 + dd) * 64 + lane2) * 8;
    *reinterpret_cast<bf16x8*>(qpk + base) = q8;
    *reinterpret_cast<bf16x8*>(kpk + base) = k8;
  }

  // phase B2: v fragment-pack (transpose gather from LDS, coalesced 16B stores)
#pragma unroll
  for (int wi = 0; wi < 4; ++wi) {
    int id = wi * 256 + t;
    int lane3 = id & 63;
    int sub = id >> 6;                // 0..15
    int kt = sub >> 3, dt = (sub >> 2) & 1, kbi = sub & 3;
    int lo3 = lane3 & 31, hi3 = lane3 >> 5;
    bf16x8 v8;
#pragma unroll
    for (int j = 0; j < 8; ++j)
      v8[j] = vs[kt * 64 + kbi * 16 + hi3 * 8 + j][dt * 32 + lo3];
    size_t vbase = ((((size_t)bh * 32 + (n0 >> 6) + kt) * 8 + dt * 4 + kbi) * 64 + lane3) * 8;
    *reinterpret_cast<bf16x8*>(vpk + vbase) = v8;
  }
}

// ---------------- flash attention: K via LDS, V direct from global (halves LDS-pipe load) ----------------
// In-block 2-way KV split, 8 waves: waves 0-3 keys [0,1024), waves 4-7 keys [1024,2048).
// K staged to LDS (shared by the group's 4 waves); V read per-wave from the packed global
// stream (coalesced 1KB bursts, L1/L2-resident) -- no LDS round-trip, real register residency.
__global__ __launch_bounds__(512, 4) void attn_kernel(const bf16* __restrict__ qpk,
                                                      const bf16* __restrict__ kpk,
                                                      const bf16* __restrict__ vpk,
                                                      bf16* __restrict__ outb) {
  __shared__ __align__(16) char kvlds[2][2][16384];   // [group][buf][K 8KB | pad]
  const int tid = threadIdx.x;
  const int lane = tid & 63;
  const int wave = tid >> 6;        // 0..7
  const int grp = wave >> 2;        // KV-split group
  const int wg = wave & 3;          // wave within group (q-tile)
  const int bid = blockIdx.x;
  const int xcd = bid & 7;          // dispatch round-robins consecutive ids across XCDs
  const int idx = bid >> 3;         // 0..63 within this XCD
  const int bh = xcd * 4 + (idx >> 4);
  const int qt = idx & 15;
  const int b = bh >> 4, h = bh & 15;
  const int lo = lane & 31;
  const int hi = lane >> 5;
  const int q0 = qt * 128 + wg * 32;

  // Q fragments (packed, coalesced; pre-scaled at rope_pack)
  bf16x8 qf[4];
#pragma unroll
  for (int d = 0; d < 4; ++d)
    qf[d] = *reinterpret_cast<const bf16x8*>(
        qpk + ((((size_t)bh * 64 + qt * 4 + wg) * 4 + d) * 64 + lane) * 8);

  f32x16 o0 = {}, o1 = {};
  float lacc[16];
#pragma unroll
  for (int r = 0; r < 16; ++r) lacc[r] = 0.f;

  auto cvtpk = [](float a, float b) {
    unsigned w;
    asm("v_cvt_pk_bf16_f32 %0, %1, %2" : "=v"(w) : "v"(a), "v"(b));
    return w;
  };

  // per-head packed streams
  const bf16* kg = kpk + (size_t)bh * 131072 + wg * 512 + lane * 8;   // staging src
  const bf16* vgl = vpk + (size_t)bh * 131072 + lane * 8;             // direct V reads

  auto stageK = [&](int til, int buf) {   // group's 4 waves stage its 8KB K tile
    char* ld = &kvlds[grp][buf][wg * 1024];
    const bf16* kk = kg + (size_t)(grp * 16 + til) * 4096;
#pragma unroll
    for (int i = 0; i < 2; ++i)
      __builtin_amdgcn_global_load_lds((const __attribute__((address_space(1))) void*)(kk + i * 2048),
                                       (__attribute__((address_space(3))) void*)(ld + i * 4096),
                                       16, 0, 0);
  };

  // one 64-key substep; V from global (issued first, consumed at PV), K from LDS
  auto substep = [&](int cur, int til) {
    const bf16* vv = vgl + (size_t)(grp * 16 + til) * 4096;
    bf16x8 vf[8];
#pragma unroll
    for (int c = 0; c < 8; ++c)
      vf[c] = *reinterpret_cast<const bf16x8*>(vv + c * 512);

    const char* base = &kvlds[grp][cur][lane * 16];
    bf16x8 kf[8];
#pragma unroll
    for (int c = 0; c < 8; ++c)
      kf[c] = *reinterpret_cast<const bf16x8*>(base + c * 1024);

    f32x16 s0 = {}, s1 = {};
#pragma unroll
    for (int d = 0; d < 4; ++d) {
      s0 = __builtin_amdgcn_mfma_f32_32x32x16_bf16(kf[d], qf[d], s0, 0, 0, 0);
      s1 = __builtin_amdgcn_mfma_f32_32x32x16_bf16(kf[4 + d], qf[d], s1, 0, 0, 0);
    }

    // P = exp2(s) directly (no max shift; Q carries the scale)
    float e[32];
#pragma unroll
    for (int r = 0; r < 16; ++r) e[r] = __builtin_amdgcn_exp2f(s0[r]);
#pragma unroll
    for (int r = 0; r < 16; ++r) e[16 + r] = __builtin_amdgcn_exp2f(s1[r]);

#pragma unroll
    for (int r = 0; r < 16; ++r) lacc[r] += e[r] + e[16 + r];

    // P^T -> bf16 B-fragments: kappa order makes this a straight cvtpk pack
    union { unsigned w[4]; bf16x8 v8; } pb[4];
#pragma unroll
    for (int c = 0; c < 4; ++c)
#pragma unroll
      for (int w = 0; w < 4; ++w)
        pb[c].w[w] = cvtpk(e[c * 8 + 2 * w], e[c * 8 + 2 * w + 1]);

    // PV: O^T[dh,q] += V^T[dh,k] P^T[k,q]
#pragma unroll
    for (int kbi = 0; kbi < 4; ++kbi) {
      o0 = __builtin_amdgcn_mfma_f32_32x32x16_bf16(vf[kbi], pb[kbi].v8, o0, 0, 0, 0);
      o1 = __builtin_amdgcn_mfma_f32_32x32x16_bf16(vf[4 + kbi], pb[kbi].v8, o1, 0, 0, 0);
    }
  };

  stageK(0, 0);
  __syncthreads();   // stage(0) landed (implicit vmcnt drain)

  for (int t = 0; t < 16; ++t) {
    const int cur = t & 1;
    if (t < 15) stageK(t + 1, cur ^ 1);   // prefetch next K tile into group's other buffer
    substep(cur, t);
    __syncthreads();   // drain stage(t+1) + protect buf reuse
  }

  // per-wave l reduction (covers this group's 1024 keys)
  float lrun;
  {
    float u[8];
#pragma unroll
    for (int r = 0; r < 8; ++r) u[r] = lacc[r] + lacc[r + 8];
#pragma unroll
    for (int r = 0; r < 4; ++r) u[r] += u[r + 4];
    lrun = (u[0] + u[2]) + (u[1] + u[3]);
    lrun += __shfl_xor(lrun, 32);
  }

  // cross-group combine via LDS (loop ended with __syncthreads -> stage data dead).
  float* scr = (float*)&kvlds[0][0][0];
  if (grp == 1) {
#pragma unroll
    for (int r = 0; r < 16; ++r) scr[r * 256 + wg * 64 + lane] = o0[r];
#pragma unroll
    for (int r = 0; r < 16; ++r) scr[(16 + r) * 256 + wg * 64 + lane] = o1[r];
    scr[8192 + wg * 64 + lane] = lrun;
  }
  __syncthreads();
  if (grp == 0) {
    float l1 = scr[8192 + wg * 64 + lane];
    float invl = 1.0f / (lrun + l1);
#pragma unroll
    for (int dt = 0; dt < 2; ++dt) {
#pragma unroll
      for (int g = 0; g < 4; ++g) {
        bf16x4 ov;
#pragma unroll
        for (int j = 0; j < 4; ++j) {
          int r = g * 4 + j;
          float mine = dt ? o1[r] : o0[r];
          float partner = scr[(dt * 16 + r) * 256 + wg * 64 + lane];
          ov[j] = (bf16)((mine + partner) * invl);
        }
        int dh = dt * 32 + g * 8 + hi * 4;
        *reinterpret_cast<bf16x4*>(outb + (size_t)(b * Nn + q0 + lo) * HID + h * DH + dh) = ov;
      }
    }
  }
}

// ---------------- launch ----------------
extern "C" void kernel_launch(void* const* d_in, const int* in_sizes, int n_in,
                              void* d_out, int out_size, void* d_ws, size_t ws_size,
                              hipStream_t stream) {
  const float* x = (const float*)d_in[0];
  const float* rope = (const float*)d_in[1];
  const float* Wqkv = (const float*)d_in[2];
  const float* Wout = (const float*)d_in[3];
  float* out = (float*)d_out;

  char* w = (char*)d_ws;
  size_t off = 0;
  auto alloc = [&](size_t bytes) -> void* {
    void* p = w + off;
    off += (bytes + 255) & ~(size_t)255;
    return p;
  };
  bf16* xb    = (bf16*)alloc((size_t)MTOK * HID * 2);
  bf16* wqkvb = (bf16*)alloc((size_t)E3 * HID * 2);
  bf16* woutb = (bf16*)alloc((size_t)HID * HID * 2);
  bf16* qkvb  = (bf16*)alloc((size_t)MTOK * E3 * 2);
  bf16* qpk   = (bf16*)alloc((size_t)Bb * Hh * Nn * DH * 2);
  bf16* kpk   = (bf16*)alloc((size_t)Bb * Hh * Nn * DH * 2);
  bf16* vpk   = (bf16*)alloc((size_t)Bb * Hh * Nn * DH * 2);
  bf16* attno = (bf16*)alloc((size_t)MTOK * HID * 2);

  constexpr int CAST4 = (MTOK * HID + E3 * HID + HID * HID) / 4;  // 2097152 float4s
  cast3_kernel<<<CAST4 / 256, 256, 0, stream>>>(x, Wqkv, Wout, xb, wqkvb, woutb);

  gemm_bt<true><<<dim3(MTOK / 128, E3 / 128), 256, 0, stream>>>(xb, wqkvb, qkvb, MTOK, E3, HID);

  rope_pack<<<dim3(Nn / 128, Bb * Hh), 256, 0, stream>>>(qkvb, rope, qpk, kpk, vpk);

  attn_kernel<<<dim3(512), 512, 0, stream>>>(qpk, kpk, vpk, attno);

  gemm_bt<false><<<dim3(MTOK / 128, HID / 128), 256, 0, stream>>>(attno, woutb, out, MTOK, HID, HID);
}

// Round 20
// 117.722 us; speedup vs baseline: 1.0443x; 1.0443x over previous
//
#include <hip/hip_runtime.h>
#include <stdint.h>
#include <stddef.h>

typedef __bf16 bf16;
typedef __bf16 bf16x2 __attribute__((ext_vector_type(2)));
typedef __bf16 bf16x4 __attribute__((ext_vector_type(4)));
typedef __bf16 bf16x8 __attribute__((ext_vector_type(8)));
typedef float f32x2 __attribute__((ext_vector_type(2)));
typedef float f32x4 __attribute__((ext_vector_type(4)));
typedef float f32x16 __attribute__((ext_vector_type(16)));

constexpr int Bb = 2, Nn = 2048, HID = 1024, Hh = 16, DH = 64;
constexpr int MTOK = Bb * Nn;   // 4096
constexpr int E3 = 3 * Hh * DH; // 3072

// ---------------- merged cast f32 -> bf16 (x, Wqkv, Wout in one launch) ----------------
__global__ void cast3_kernel(const float* __restrict__ x, const float* __restrict__ wqkv,
                             const float* __restrict__ wout,
                             bf16* __restrict__ xb, bf16* __restrict__ wqkvb,
                             bf16* __restrict__ woutb) {
  constexpr int N1 = MTOK * HID / 4;        // x float4s
  constexpr int N2 = N1 + E3 * HID / 4;     // + Wqkv
  int i = blockIdx.x * 256 + threadIdx.x;   // 0 .. 2097151
  const float* src;
  bf16* dst;
  int off;
  if (i < N1)      { src = x;    dst = xb;    off = i; }
  else if (i < N2) { src = wqkv; dst = wqkvb; off = i - N1; }
  else             { src = wout; dst = woutb; off = i - N2; }
  f32x4 v = reinterpret_cast<const f32x4*>(src)[off];
  bf16x4 o;
#pragma unroll
  for (int j = 0; j < 4; ++j) o[j] = (bf16)v[j];
  reinterpret_cast<bf16x4*>(dst)[off] = o;
}

// ---------------- BT GEMM: C[M,N] = A[M,K] * Bt[N,K]^T ----------------
// BK=64 via two 32-col halves per K-step (R15-proven); 32 MFMA per barrier pair.
template <bool OUT_BF16>
__global__ __launch_bounds__(256) void gemm_bt(const bf16* __restrict__ A,
                                               const bf16* __restrict__ Bt,
                                               void* __restrict__ Cp,
                                               int M, int N, int K) {
  __shared__ __align__(16) bf16 As[2][128 * 32];
  __shared__ __align__(16) bf16 Bs[2][128 * 32];
  const int tid = threadIdx.x;
  const int lane = tid & 63;
  const int wave = tid >> 6;
  const int wr = wave >> 1, wc = wave & 1;
  const int bm = blockIdx.x, bn = blockIdx.y;
  const int frow = lane & 15;
  const int fk = (lane >> 4) * 8;
  const int c0 = wave * 128 + lane;

  f32x4 acc[4][4] = {};

  for (int k0 = 0; k0 < K; k0 += 64) {
#pragma unroll
    for (int hk = 0; hk < 2; ++hk)
#pragma unroll
      for (int i = 0; i < 2; ++i) {
        int c = c0 + i * 64;             // chunk 0..511 within the half, 16B each
        int row = c >> 2;
        int col = (c & 3) * 8;
        const bf16* ga = A + (size_t)(bm * 128 + row) * K + k0 + hk * 32 + col;
        const bf16* gb = Bt + (size_t)(bn * 128 + row) * K + k0 + hk * 32 + col;
        __builtin_amdgcn_global_load_lds((const __attribute__((address_space(1))) void*)ga,
                                         (__attribute__((address_space(3))) void*)(As[hk] + c * 8),
                                         16, 0, 0);
        __builtin_amdgcn_global_load_lds((const __attribute__((address_space(1))) void*)gb,
                                         (__attribute__((address_space(3))) void*)(Bs[hk] + c * 8),
                                         16, 0, 0);
      }
    __syncthreads();
#pragma unroll
    for (int hk = 0; hk < 2; ++hk) {
      bf16x8 af[4], bfr[4];
#pragma unroll
      for (int m = 0; m < 4; ++m)
        af[m] = *reinterpret_cast<const bf16x8*>(As[hk] + (wr * 64 + m * 16 + frow) * 32 + fk);
#pragma unroll
      for (int n = 0; n < 4; ++n)
        bfr[n] = *reinterpret_cast<const bf16x8*>(Bs[hk] + (wc * 64 + n * 16 + frow) * 32 + fk);
#pragma unroll
      for (int m = 0; m < 4; ++m)
#pragma unroll
        for (int n = 0; n < 4; ++n)
          acc[m][n] = __builtin_amdgcn_mfma_f32_16x16x32_bf16(af[m], bfr[n], acc[m][n], 0, 0, 0);
    }
    __syncthreads();
  }

  const int r0 = bm * 128 + wr * 64;
  const int cc0 = bn * 128 + wc * 64;
#pragma unroll
  for (int m = 0; m < 4; ++m)
#pragma unroll
    for (int n = 0; n < 4; ++n)
#pragma unroll
      for (int r = 0; r < 4; ++r) {
        int row = r0 + m * 16 + (lane >> 4) * 4 + r;
        int col = cc0 + n * 16 + frow;
        if (OUT_BF16)
          ((bf16*)Cp)[(size_t)row * N + col] = (bf16)acc[m][n][r];
        else
          ((float*)Cp)[(size_t)row * N + col] = acc[m][n][r];
      }
}

// K-row permutation: slot a holds key kappa(a); makes the S^T accumulator land
// directly in the PV B-fragment layout (no cross-lane exchange needed).
__device__ __forceinline__ int kappa(int a) {
  return (((a >> 2) ^ (a >> 3)) & 1) ? (a ^ 12) : a;
}

// ---------------- RoPE + fragment-pack ----------------
// Emits Q,K,V in MFMA-fragment-packed order so attention loads are base+lane*16B (coalesced).
// K rows kappa-permuted within each 32-row block. Q pre-scaled by dh^-0.5*log2(e).
__global__ __launch_bounds__(256) void rope_pack(const bf16* __restrict__ qkvb,
                                                 const float* __restrict__ rope,
                                                 bf16* __restrict__ qpk,
                                                 bf16* __restrict__ kpk,
                                                 bf16* __restrict__ vpk) {
  __shared__ bf16 qs[128][66];
  __shared__ bf16 ks[128][66];
  __shared__ bf16 vs[128][66];
  const int bh = blockIdx.y;
  const int b = bh >> 4;
  const int h = bh & 15;
  const int n0 = blockIdx.x * 128;
  const int t = threadIdx.x;

  constexpr float QS = 0.125f * 1.44269504088896340736f;  // folded into Q

  // phase A: rope + stage to LDS
  for (int it = 0; it < 16; ++it) {
    int p = it * 256 + t;   // (row 0..127) x (pair 0..31)
    int nl = p >> 5, i = p & 31;
    int n = n0 + nl;
    size_t rowbase = (size_t)(b * Nn + n);
    const bf16* src = qkvb + rowbase * E3 + h * DH + 2 * i;
    f32x2 cs = *reinterpret_cast<const f32x2*>(rope + rowbase * DH + 2 * i);
    float c = cs[0], sn = cs[1];
    bf16x2 qv = *reinterpret_cast<const bf16x2*>(src);
    bf16x2 kv = *reinterpret_cast<const bf16x2*>(src + HID);
    bf16x2 vv = *reinterpret_cast<const bf16x2*>(src + 2 * HID);
    float q0 = (float)qv[0], q1 = (float)qv[1];
    float k0 = (float)kv[0], k1 = (float)kv[1];
    qs[nl][2 * i]     = (bf16)((q0 * c - q1 * sn) * QS);
    qs[nl][2 * i + 1] = (bf16)((q1 * c + q0 * sn) * QS);
    ks[nl][2 * i]     = (bf16)(k0 * c - k1 * sn);
    ks[nl][2 * i + 1] = (bf16)(k1 * c + k0 * sn);
    vs[nl][2 * i]     = vv[0];
    vs[nl][2 * i + 1] = vv[1];
  }
  __syncthreads();

  // phase B1: q/k fragment-pack (coalesced 16B stores); K rows kappa-permuted
  const int lane2 = t & 63;
  const int dd = t >> 6;              // 0..3
  const int lo2 = lane2 & 31, hi2 = lane2 >> 5;
  const int lok = kappa(lo2);
#pragma unroll
  for (int kbq = 0; kbq < 4; ++kbq) {
    int col = dd * 16 + hi2 * 8;
    bf16x8 q8 = *reinterpret_cast<const bf16x8*>(&qs[kbq * 32 + lo2][col]);
    bf16x8 k8 = *reinterpret_cast<const bf16x8*>(&ks[kbq * 32 + lok][col]);
    size_t base = ((((size_t)bh * 64 + (n0 >> 5) + kbq) * 4 + dd) * 64 + lane2) * 8;
    *reinterpret_cast<bf16x8*>(qpk + base) = q8;
    *reinterpret_cast<bf16x8*>(kpk + base) = k8;
  }

  // phase B2: v fragment-pack (transpose gather from LDS, coalesced 16B stores)
#pragma unroll
  for (int wi = 0; wi < 4; ++wi) {
    int id = wi * 256 + t;
    int lane3 = id & 63;
    int sub = id >> 6;                // 0..15
    int kt = sub >> 3, dt = (sub >> 2) & 1, kbi = sub & 3;
    int lo3 = lane3 & 31, hi3 = lane3 >> 5;
    bf16x8 v8;
#pragma unroll
    for (int j = 0; j < 8; ++j)
      v8[j] = vs[kt * 64 + kbi * 16 + hi3 * 8 + j][dt * 32 + lo3];
    size_t vbase = ((((size_t)bh * 32 + (n0 >> 6) + kt) * 8 + dt * 4 + kbi) * 64 + lane3) * 8;
    *reinterpret_cast<bf16x8*>(vpk + vbase) = v8;
  }
}

// ---------------- flash attention: in-block 2-way KV split, 8 waves (R17-proven best) ----------------
// Waves 0-3 process keys [0,1024), waves 4-7 keys [1024,2048), same q-tiles.
// Each group runs the R13-proven 64-key double-buffered LDS stream (2 groups x 2 bufs x 16KB).
// Max-free softmax => combine is just (O0+O1)/(l0+l1) via one LDS exchange. 4 waves/SIMD.
__global__ __launch_bounds__(512, 4) void attn_kernel(const bf16* __restrict__ qpk,
                                                      const bf16* __restrict__ kpk,
                                                      const bf16* __restrict__ vpk,
                                                      bf16* __restrict__ outb) {
  __shared__ __align__(16) char kvlds[2][2][16384];   // [group][buf][K 8KB | V 8KB]
  const int tid = threadIdx.x;
  const int lane = tid & 63;
  const int wave = tid >> 6;        // 0..7
  const int grp = wave >> 2;        // KV-split group
  const int wg = wave & 3;          // wave within group (q-tile)
  const int bid = blockIdx.x;
  const int xcd = bid & 7;          // dispatch round-robins consecutive ids across XCDs
  const int idx = bid >> 3;         // 0..63 within this XCD
  const int bh = xcd * 4 + (idx >> 4);
  const int qt = idx & 15;
  const int b = bh >> 4, h = bh & 15;
  const int lo = lane & 31;
  const int hi = lane >> 5;
  const int q0 = qt * 128 + wg * 32;

  // Q fragments (packed, coalesced; pre-scaled at rope_pack)
  bf16x8 qf[4];
#pragma unroll
  for (int d = 0; d < 4; ++d)
    qf[d] = *reinterpret_cast<const bf16x8*>(
        qpk + ((((size_t)bh * 64 + qt * 4 + wg) * 4 + d) * 64 + lane) * 8);

  f32x16 o0 = {}, o1 = {};
  float lacc[16];
#pragma unroll
  for (int r = 0; r < 16; ++r) lacc[r] = 0.f;

  auto cvtpk = [](float a, float b) {
    unsigned w;
    asm("v_cvt_pk_bf16_f32 %0, %1, %2" : "=v"(w) : "v"(a), "v"(b));
    return w;
  };

  // per-head packed streams: 1KB chunks; group g's keys start at chunk g*16
  const bf16* kg = kpk + (size_t)bh * 131072 + wg * 512 + lane * 8;
  const bf16* vg = vpk + (size_t)bh * 131072 + wg * 512 + lane * 8;

  auto stage = [&](int til, int buf) {   // group's 4 waves stage its 16KB tile
    char* ld = &kvlds[grp][buf][wg * 1024];
    const bf16* kk = kg + (size_t)(grp * 16 + til) * 4096;
    const bf16* vv = vg + (size_t)(grp * 16 + til) * 4096;
#pragma unroll
    for (int i = 0; i < 2; ++i) {
      __builtin_amdgcn_global_load_lds((const __attribute__((address_space(1))) void*)(kk + i * 2048),
                                       (__attribute__((address_space(3))) void*)(ld + i * 4096),
                                       16, 0, 0);
      __builtin_amdgcn_global_load_lds((const __attribute__((address_space(1))) void*)(vv + i * 2048),
                                       (__attribute__((address_space(3))) void*)(ld + 8192 + i * 4096),
                                       16, 0, 0);
    }
  };

  // one 64-key substep: byte-identical math to the R13/R16-proven body (V at +8192)
  auto substep = [&](int cur) {
    const char* base = &kvlds[grp][cur][lane * 16];
    bf16x8 kf[8], vf[8];
#pragma unroll
    for (int c = 0; c < 8; ++c) {
      kf[c] = *reinterpret_cast<const bf16x8*>(base + c * 1024);
      vf[c] = *reinterpret_cast<const bf16x8*>(base + 8192 + c * 1024);
    }

    f32x16 s0 = {}, s1 = {};
#pragma unroll
    for (int d = 0; d < 4; ++d) {
      s0 = __builtin_amdgcn_mfma_f32_32x32x16_bf16(kf[d], qf[d], s0, 0, 0, 0);
      s1 = __builtin_amdgcn_mfma_f32_32x32x16_bf16(kf[4 + d], qf[d], s1, 0, 0, 0);
    }

    // P = exp2(s) directly (no max shift; Q carries the scale)
    float e[32];
#pragma unroll
    for (int r = 0; r < 16; ++r) e[r] = __builtin_amdgcn_exp2f(s0[r]);
#pragma unroll
    for (int r = 0; r < 16; ++r) e[16 + r] = __builtin_amdgcn_exp2f(s1[r]);

#pragma unroll
    for (int r = 0; r < 16; ++r) lacc[r] += e[r] + e[16 + r];

    // P^T -> bf16 B-fragments: kappa order makes this a straight cvtpk pack
    union { unsigned w[4]; bf16x8 v8; } pb[4];
#pragma unroll
    for (int c = 0; c < 4; ++c)
#pragma unroll
      for (int w = 0; w < 4; ++w)
        pb[c].w[w] = cvtpk(e[c * 8 + 2 * w], e[c * 8 + 2 * w + 1]);

    // PV: O^T[dh,q] += V^T[dh,k] P^T[k,q]
#pragma unroll
    for (int kbi = 0; kbi < 4; ++kbi) {
      o0 = __builtin_amdgcn_mfma_f32_32x32x16_bf16(vf[kbi], pb[kbi].v8, o0, 0, 0, 0);
      o1 = __builtin_amdgcn_mfma_f32_32x32x16_bf16(vf[4 + kbi], pb[kbi].v8, o1, 0, 0, 0);
    }
  };

  stage(0, 0);
  __syncthreads();   // stage(0) landed (implicit vmcnt drain)

  for (int t = 0; t < 16; ++t) {
    const int cur = t & 1;
    if (t < 15) stage(t + 1, cur ^ 1);   // prefetch next tile into group's other buffer
    substep(cur);
    __syncthreads();   // drain stage(t+1) + protect buf reuse
  }

  // per-wave l reduction (covers this group's 1024 keys)
  float lrun;
  {
    float u[8];
#pragma unroll
    for (int r = 0; r < 8; ++r) u[r] = lacc[r] + lacc[r + 8];
#pragma unroll
    for (int r = 0; r < 4; ++r) u[r] += u[r + 4];
    lrun = (u[0] + u[2]) + (u[1] + u[3]);
    lrun += __shfl_xor(lrun, 32);
  }

  // cross-group combine via LDS (loop ended with __syncthreads -> stage data dead).
  // layout: O in [0,8192) f32 as [r][wg*64+lane] (conflict-free), l at [8192,8448).
  float* scr = (float*)&kvlds[0][0][0];
  if (grp == 1) {
#pragma unroll
    for (int r = 0; r < 16; ++r) scr[r * 256 + wg * 64 + lane] = o0[r];
#pragma unroll
    for (int r = 0; r < 16; ++r) scr[(16 + r) * 256 + wg * 64 + lane] = o1[r];
    scr[8192 + wg * 64 + lane] = lrun;
  }
  __syncthreads();
  if (grp == 0) {
    float l1 = scr[8192 + wg * 64 + lane];
    float invl = 1.0f / (lrun + l1);
#pragma unroll
    for (int dt = 0; dt < 2; ++dt) {
#pragma unroll
      for (int g = 0; g < 4; ++g) {
        bf16x4 ov;
#pragma unroll
        for (int j = 0; j < 4; ++j) {
          int r = g * 4 + j;
          float mine = dt ? o1[r] : o0[r];
          float partner = scr[(dt * 16 + r) * 256 + wg * 64 + lane];
          ov[j] = (bf16)((mine + partner) * invl);
        }
        int dh = dt * 32 + g * 8 + hi * 4;
        *reinterpret_cast<bf16x4*>(outb + (size_t)(b * Nn + q0 + lo) * HID + h * DH + dh) = ov;
      }
    }
  }
}

// ---------------- launch ----------------
extern "C" void kernel_launch(void* const* d_in, const int* in_sizes, int n_in,
                              void* d_out, int out_size, void* d_ws, size_t ws_size,
                              hipStream_t stream) {
  const float* x = (const float*)d_in[0];
  const float* rope = (const float*)d_in[1];
  const float* Wqkv = (const float*)d_in[2];
  const float* Wout = (const float*)d_in[3];
  float* out = (float*)d_out;

  char* w = (char*)d_ws;
  size_t off = 0;
  auto alloc = [&](size_t bytes) -> void* {
    void* p = w + off;
    off += (bytes + 255) & ~(size_t)255;
    return p;
  };
  bf16* xb    = (bf16*)alloc((size_t)MTOK * HID * 2);
  bf16* wqkvb = (bf16*)alloc((size_t)E3 * HID * 2);
  bf16* woutb = (bf16*)alloc((size_t)HID * HID * 2);
  bf16* qkvb  = (bf16*)alloc((size_t)MTOK * E3 * 2);
  bf16* qpk   = (bf16*)alloc((size_t)Bb * Hh * Nn * DH * 2);
  bf16* kpk   = (bf16*)alloc((size_t)Bb * Hh * Nn * DH * 2);
  bf16* vpk   = (bf16*)alloc((size_t)Bb * Hh * Nn * DH * 2);
  bf16* attno = (bf16*)alloc((size_t)MTOK * HID * 2);

  constexpr int CAST4 = (MTOK * HID + E3 * HID + HID * HID) / 4;  // 2097152 float4s
  cast3_kernel<<<CAST4 / 256, 256, 0, stream>>>(x, Wqkv, Wout, xb, wqkvb, woutb);

  gemm_bt<true><<<dim3(MTOK / 128, E3 / 128), 256, 0, stream>>>(xb, wqkvb, qkvb, MTOK, E3, HID);

  rope_pack<<<dim3(Nn / 128, Bb * Hh), 256, 0, stream>>>(qkvb, rope, qpk, kpk, vpk);

  attn_kernel<<<dim3(512), 512, 0, stream>>>(qpk, kpk, vpk, attno);

  gemm_bt<false><<<dim3(MTOK / 128, HID / 128), 256, 0, stream>>>(attno, woutb, out, MTOK, HID, HID);
}